// Round 1
// baseline (239.430 us; speedup 1.0000x reference)
//
#include <hip/hip_runtime.h>
#include <math.h>

#define HWSZ 6400
#define WIMG 80
#define HIMG 80
#define BEPS 1e-5f

typedef __attribute__((ext_vector_type(8))) short short8;
typedef __attribute__((ext_vector_type(4))) float f32x4;
typedef __attribute__((ext_vector_type(4))) unsigned u32x4;

__device__ __forceinline__ unsigned short f2b(float f) {
    unsigned u = __builtin_bit_cast(unsigned, f);
    u += 0x7fffu + ((u >> 16) & 1u);
    return (unsigned short)(u >> 16);
}
__device__ __forceinline__ float b2f(unsigned short h) {
    unsigned u = ((unsigned)h) << 16;
    return __builtin_bit_cast(float, u);
}
__device__ __forceinline__ float silu_f(float t) { return t / (1.f + __expf(-t)); }

// B-fragment LDS layout for cv1: [kstep(sub)][ntile][n16][q-octet][8] with pad
#define BPOS(sub, nt, n16, q) (((((sub)*4 + (nt))*16 + (n16))*40) + (q)*8)

// ---------------- prep: BN-fold + bf16 A-fragment prepack -------------------
__global__ __launch_bounds__(256) void k_prep(
    const float* __restrict__ cv1w, const float* __restrict__ g1, const float* __restrict__ b1,
    const float* __restrict__ m1, const float* __restrict__ v1,
    const float* __restrict__ offw, const float* __restrict__ offb,
    const float* __restrict__ dcnw, const float* __restrict__ dcnb,
    const float* __restrict__ g2, const float* __restrict__ b2,
    const float* __restrict__ m2, const float* __restrict__ v2,
    const float* __restrict__ cv2w, const float* __restrict__ g3, const float* __restrict__ b3,
    const float* __restrict__ m3, const float* __restrict__ v3,
    unsigned short* __restrict__ apk1, unsigned short* __restrict__ apko,
    unsigned short* __restrict__ apkd, unsigned short* __restrict__ apk2,
    float* __restrict__ bias1, float* __restrict__ biaso,
    float* __restrict__ bias2, float* __restrict__ bias3)
{
    int idx = blockIdx.x * 256 + threadIdx.x;
    if (idx < 32768) {                       // cv1: [8 mt][8 ks][64][8], K = 256 ch
        int j = idx & 7, L = (idx >> 3) & 63, ks = (idx >> 9) & 7, mt = idx >> 12;
        int o = mt * 16 + (L & 15), k = ks * 32 + (L >> 4) * 8 + j;
        float inv = g1[o] * rsqrtf(v1[o] + BEPS);
        apk1[idx] = f2b(cv1w[o * 256 + k] * inv);
    } else if (idx < 69632) {                // off: [2 mt][36 ks][64][8], k' = n*128+c
        int t = idx - 32768;
        int j = t & 7, L = (t >> 3) & 63;
        int mt = t / 18432, rem = t % 18432, ks = rem >> 9;
        int o = mt * 16 + (L & 15);
        int kp = ks * 32 + (L >> 4) * 8 + j;
        int n = kp >> 7, c = kp & 127;
        float wv = (o < 27) ? offw[(size_t)(o * 128 + c) * 9 + n] : 0.f;
        apko[t] = f2b(wv);
    } else if (idx < 217088) {               // dcn: [8 mt][36 ks][64][8], k' = n*128+c, BN2 fold
        int t = idx - 69632;
        int j = t & 7, L = (t >> 3) & 63;
        int mt = t / 18432, rem = t % 18432, ks = rem >> 9;
        int o = mt * 16 + (L & 15);
        int kp = ks * 32 + (L >> 4) * 8 + j;
        int n = kp >> 7, c = kp & 127;
        float inv = g2[o] * rsqrtf(v2[o] + BEPS);
        apkd[t] = f2b(dcnw[(size_t)(o * 128 + c) * 9 + n] * inv);
    } else if (idx < 249856) {               // cv2: [16 mt][4 ks][64][8], BN3 fold
        int t = idx - 217088;
        int j = t & 7, L = (t >> 3) & 63, ks = (t >> 9) & 3, mt = t >> 11;
        int o = mt * 16 + (L & 15), k = ks * 32 + (L >> 4) * 8 + j;
        float inv = g3[o] * rsqrtf(v3[o] + BEPS);
        apk2[t] = f2b(cv2w[o * 128 + k] * inv);
    } else if (idx < 250395) {               // biases
        int t = idx - 249856;
        if (t < 128) { float inv = g1[t] * rsqrtf(v1[t] + BEPS); bias1[t] = b1[t] - m1[t] * inv; }
        else if (t < 155) { biaso[t - 128] = offb[t - 128]; }
        else if (t < 283) { int o = t - 155; float inv = g2[o] * rsqrtf(v2[o] + BEPS);
                            bias2[o] = dcnb[o] * inv + b2[o] - m2[o] * inv; }
        else { int o = t - 283; float inv = g3[o] * rsqrtf(v3[o] + BEPS); bias3[o] = b3[o] - m3[o] * inv; }
    }
}

// ---------------- cv1: 1x1 (256->128) + bn1 + silu -> y1t (pixel-major bf16) ----
__global__ __launch_bounds__(256) void k_cv1(
    const float* __restrict__ x, const unsigned short* __restrict__ apk1,
    const float* __restrict__ bias1, unsigned short* __restrict__ y1t)
{
    __shared__ __align__(16) unsigned short sB[20480];   // 8 ks * 4 nt * 16 * 40
    int blk = blockIdx.x;
    int b = blk / 100, pt = blk % 100;
    int p0 = pt * 64;
    int tid = threadIdx.x;
    int lane = tid & 63;
    int w = tid >> 6;
    {
        int px = lane, q = w;
        const float* xb = x + (size_t)b * 256 * HWSZ + p0 + px;
        for (int ks = 0; ks < 8; ++ks) {
            short8 v;
#pragma unroll
            for (int j = 0; j < 8; ++j)
                v[j] = (short)f2b(xb[(size_t)(ks * 32 + q * 8 + j) * HWSZ]);
            *(short8*)&sB[((ks * 4 + (px >> 4)) * 16 + (px & 15)) * 40 + q * 8] = v;
        }
    }
    __syncthreads();
    int n16 = lane & 15, qd = lane >> 4;
    f32x4 acc[2][4];
#pragma unroll
    for (int mi = 0; mi < 2; ++mi)
#pragma unroll
        for (int nt = 0; nt < 4; ++nt) acc[mi][nt] = (f32x4){0.f, 0.f, 0.f, 0.f};
    for (int ks = 0; ks < 8; ++ks) {
        short8 bf[4];
#pragma unroll
        for (int nt = 0; nt < 4; ++nt)
            bf[nt] = *(const short8*)&sB[((ks * 4 + nt) * 16 + n16) * 40 + qd * 8];
#pragma unroll
        for (int mi = 0; mi < 2; ++mi) {
            int mt = w * 2 + mi;
            short8 af = *(const short8*)&apk1[(size_t)((mt * 8 + ks) * 64 + lane) * 8];
#pragma unroll
            for (int nt = 0; nt < 4; ++nt)
                acc[mi][nt] = __builtin_amdgcn_mfma_f32_16x16x32_bf16(af, bf[nt], acc[mi][nt], 0, 0, 0);
        }
    }
    __syncthreads();
#pragma unroll
    for (int mi = 0; mi < 2; ++mi)
#pragma unroll
        for (int nt = 0; nt < 4; ++nt)
#pragma unroll
            for (int r = 0; r < 4; ++r) {
                int o = w * 32 + mi * 16 + qd * 4 + r;
                float sv = silu_f(acc[mi][nt][r] + bias1[o]);
                sB[(nt * 16 + n16) * 136 + o] = f2b(sv);
            }
    __syncthreads();
    {
        int px = tid >> 2, qq = tid & 3;
        unsigned short* ytb = y1t + ((size_t)b * HWSZ + p0 + px) * 128;
#pragma unroll
        for (int seg = 0; seg < 4; ++seg) {
            short8 v = *(const short8*)&sB[px * 136 + qq * 32 + seg * 8];
            *(short8*)&ytb[qq * 32 + seg * 8] = v;
        }
    }
}

// ---------------- off: 3x3 conv (128->27) + bias, sigmoid on mask ------------
// NEW: stage the 64-px tile + full 3x3 halo (226 rows) into LDS ONCE, then all
// 9 taps read LDS. One barrier total (was 18). Zero row 226 handles padding.
__global__ __launch_bounds__(256) void k_off(
    const unsigned short* __restrict__ y1t, const unsigned short* __restrict__ apko,
    const float* __restrict__ biaso, float* __restrict__ raw)
{
    __shared__ __align__(16) unsigned short sV[227 * 136];   // 61,744 B
    int blk = blockIdx.x;
    int b = blk / 100, pt = blk % 100;
    int p0 = pt * 64;
    int tid = threadIdx.x;
    const unsigned short* yb = y1t + (size_t)b * HWSZ * 128;
    // stage rows 0..225 = pixels p0-81 .. p0+144 (clamped; OOB rows never read)
    for (int c = tid; c < 226 * 16; c += 256) {
        int row = c >> 4, col = c & 15;
        int sp = p0 - 81 + row;
        sp = min(max(sp, 0), HWSZ - 1);
        *(short8*)&sV[row * 136 + col * 8] = *(const short8*)&yb[(size_t)sp * 128 + col * 8];
    }
    if (tid < 16) {                       // zero row (conv padding)
        short8 z = {0, 0, 0, 0, 0, 0, 0, 0};
        *(short8*)&sV[226 * 136 + tid * 8] = z;
    }
    __syncthreads();

    int lane = tid & 63, w = tid >> 6;
    int n16 = lane & 15, qd = lane >> 4;
    int p = p0 + w * 16 + n16;
    int h = p / WIMG, wx = p % WIMG;
    f32x4 acc[2];
    acc[0] = (f32x4){0.f, 0.f, 0.f, 0.f};
    acc[1] = (f32x4){0.f, 0.f, 0.f, 0.f};
#pragma unroll
    for (int n = 0; n < 9; ++n) {
        int dh = n / 3 - 1, dw = n % 3 - 1;
        int hh = h + dh, ww = wx + dw;
        bool valid = ((unsigned)hh < HIMG) && ((unsigned)ww < WIMG);
        int row = valid ? (81 + w * 16 + n16 + dh * WIMG + dw) : 226;
        const unsigned short* rV = &sV[row * 136 + qd * 8];
#pragma unroll
        for (int s = 0; s < 4; ++s) {
            int ks = n * 4 + s;
            short8 bf = *(const short8*)&rV[s * 32];
#pragma unroll
            for (int mi = 0; mi < 2; ++mi) {
                short8 af = *(const short8*)&apko[(size_t)((mi * 36 + ks) * 64 + lane) * 8];
                acc[mi] = __builtin_amdgcn_mfma_f32_16x16x32_bf16(af, bf, acc[mi], 0, 0, 0);
            }
        }
    }
    float* rb = raw + (size_t)b * 27 * HWSZ + p0 + w * 16 + n16;
#pragma unroll
    for (int mi = 0; mi < 2; ++mi)
#pragma unroll
        for (int r = 0; r < 4; ++r) {
            int o = mi * 16 + qd * 4 + r;
            if (o < 27) {
                float t = acc[mi][r] + biaso[o];
                if (o >= 18) t = 1.f / (1.f + __expf(-t));
                rb[(size_t)o * HWSZ] = t;
            }
        }
}

// ---------------- dcn: DCNv2 + bn2 + silu -> zt (pixel-major bf16) -----------
// NEW: P=32 tiles (grid 1600, ~6 blocks/CU by 24 KB LDS), double-buffered
// B-tile -> ONE barrier per tap, 8 threads/pixel gather (contiguous 32 B per
// corner), v_cvt_pk_bf16_f32 packing, 136-pitch pixel-major LDS (<=2-way banks).
__global__ __launch_bounds__(256) void k_dcn(
    const unsigned short* __restrict__ y1t, const float* __restrict__ raw,
    const unsigned short* __restrict__ apkd, const float* __restrict__ bias2,
    unsigned short* __restrict__ zt)
{
    __shared__ float swgt[4][9][32];
    __shared__ unsigned short sidx[4][9][32];
    __shared__ __align__(16) unsigned short sV[2][32 * 136];   // 2 x 8704 B
    int blk = blockIdx.x;
    int b = blk / 200, pt = blk % 200;
    int p0 = pt * 32;
    int tid = threadIdx.x;

    // stage 1: decode offsets -> 4 corner (idx, weight) per (tap, pixel)
    for (int i = tid; i < 288; i += 256) {
        int n = i >> 5, pp = i & 31;
        int p = p0 + pp;
        int h = p / WIMG, wx = p % WIMG;
        const float* rb = raw + (size_t)b * 27 * HWSZ + p;
        float dy = rb[(size_t)(2 * n) * HWSZ];
        float dx = rb[(size_t)(2 * n + 1) * HWSZ];
        float mk = rb[(size_t)(18 + n) * HWSZ];
        float py = (float)(h - 1 + n / 3) + dy;
        float px = (float)(wx - 1 + n % 3) + dx;
        float y0f = floorf(py), x0f = floorf(px);
        float fy = py - y0f, fx = px - x0f;
        int y0 = (int)y0f, x0 = (int)x0f;
#pragma unroll
        for (int k = 0; k < 4; ++k) {
            int yy = y0 + (k >> 1);
            int xx = x0 + (k & 1);
            bool valid = ((unsigned)yy < HIMG) && ((unsigned)xx < WIMG);
            float wk = ((k >> 1) ? fy : 1.f - fy) * ((k & 1) ? fx : 1.f - fx);
            wk = valid ? wk * mk : 0.f;
            int yc = min(max(yy, 0), HIMG - 1);
            int xc = min(max(xx, 0), WIMG - 1);
            sidx[k][n][pp] = (unsigned short)(yc * WIMG + xc);
            swgt[k][n][pp] = wk;
        }
    }
    __syncthreads();

    int lane = tid & 63, w = tid >> 6;
    int n16 = lane & 15, qd = lane >> 4;
    int pxl = tid >> 3, q = tid & 7;          // 8 threads per pixel, 16 ch each
    int sub = q & 3, qd0 = (q >> 2) * 2;
    int c0 = sub * 32 + qd0 * 8;              // contiguous 16-ch span
    const unsigned short* yb = y1t + (size_t)b * HWSZ * 128;
    f32x4 acc[2][2];
#pragma unroll
    for (int mi = 0; mi < 2; ++mi)
#pragma unroll
        for (int nt = 0; nt < 2; ++nt) acc[mi][nt] = (f32x4){0.f, 0.f, 0.f, 0.f};

    for (int n = 0; n < 9; ++n) {
        // gather + bilinear for this thread's 16 channels of pixel pxl
        float av[16];
#pragma unroll
        for (int j = 0; j < 16; ++j) av[j] = 0.f;
#pragma unroll
        for (int k = 0; k < 4; ++k) {
            float wk = swgt[k][n][pxl];
            const unsigned short* ys = yb + (size_t)sidx[k][n][pxl] * 128 + c0;
            u32x4 u0 = *(const u32x4*)ys;
            u32x4 u1 = *(const u32x4*)(ys + 8);
#pragma unroll
            for (int t = 0; t < 4; ++t) {
                unsigned ua = u0[t], ub = u1[t];
                av[2 * t]     = fmaf(wk, __builtin_bit_cast(float, ua << 16), av[2 * t]);
                av[2 * t + 1] = fmaf(wk, __builtin_bit_cast(float, ua & 0xffff0000u), av[2 * t + 1]);
                av[8 + 2 * t]     = fmaf(wk, __builtin_bit_cast(float, ub << 16), av[8 + 2 * t]);
                av[8 + 2 * t + 1] = fmaf(wk, __builtin_bit_cast(float, ub & 0xffff0000u), av[8 + 2 * t + 1]);
            }
        }
        unsigned pk[8];
#pragma unroll
        for (int t = 0; t < 8; ++t)
            asm("v_cvt_pk_bf16_f32 %0, %1, %2" : "=v"(pk[t]) : "v"(av[2 * t]), "v"(av[2 * t + 1]));
        {
            unsigned short* dst = &sV[n & 1][pxl * 136 + c0];
            u32x4 w0 = {pk[0], pk[1], pk[2], pk[3]};
            u32x4 w1 = {pk[4], pk[5], pk[6], pk[7]};
            *(u32x4*)dst = w0;
            *(u32x4*)(dst + 8) = w1;
        }
        __syncthreads();
        const unsigned short* sb = sV[n & 1];
#pragma unroll
        for (int s = 0; s < 4; ++s) {
            int ks = n * 4 + s;
            short8 bf0 = *(const short8*)&sb[(n16) * 136 + s * 32 + qd * 8];
            short8 bf1 = *(const short8*)&sb[(16 + n16) * 136 + s * 32 + qd * 8];
#pragma unroll
            for (int mi = 0; mi < 2; ++mi) {
                short8 af = *(const short8*)&apkd[(size_t)(((2 * w + mi) * 36 + ks) * 64 + lane) * 8];
                acc[mi][0] = __builtin_amdgcn_mfma_f32_16x16x32_bf16(af, bf0, acc[mi][0], 0, 0, 0);
                acc[mi][1] = __builtin_amdgcn_mfma_f32_16x16x32_bf16(af, bf1, acc[mi][1], 0, 0, 0);
            }
        }
        // no second barrier: next tap writes the OTHER buffer
    }
    __syncthreads();
    // epilogue: bn2(fused)+silu, transpose to pixel-major bf16 via LDS
    unsigned short* sE = sV[0];
#pragma unroll
    for (int mi = 0; mi < 2; ++mi)
#pragma unroll
        for (int nt = 0; nt < 2; ++nt)
#pragma unroll
            for (int r = 0; r < 4; ++r) {
                int o = w * 32 + mi * 16 + qd * 4 + r;
                float sv = silu_f(acc[mi][nt][r] + bias2[o]);
                sE[(nt * 16 + n16) * 136 + o] = f2b(sv);
            }
    __syncthreads();
    {
        int px = tid >> 3, qq = tid & 7;
        unsigned short* zb = zt + ((size_t)b * HWSZ + p0 + px) * 128;
#pragma unroll
        for (int sg = 0; sg < 2; ++sg) {
            short8 v = *(const short8*)&sE[px * 136 + (qq * 2 + sg) * 8];
            *(short8*)&zb[(qq * 2 + sg) * 8] = v;
        }
    }
}

// ---------------- cv2: 1x1 (128->256) + bn3 + silu + residual ----------------
__global__ __launch_bounds__(256) void k_cv2(
    const unsigned short* __restrict__ zt, const float* __restrict__ x,
    const unsigned short* __restrict__ apk2, const float* __restrict__ bias3,
    float* __restrict__ out)
{
    int blk = blockIdx.x;
    int b = blk / 100, pt = blk % 100;
    int p0 = pt * 64;
    int tid = threadIdx.x;
    int lane = tid & 63, w = tid >> 6;
    int n16 = lane & 15, qd = lane >> 4;
    const unsigned short* zb = zt + ((size_t)b * HWSZ + p0) * 128;
    f32x4 acc[4][4];
#pragma unroll
    for (int mi = 0; mi < 4; ++mi)
#pragma unroll
        for (int nt = 0; nt < 4; ++nt) acc[mi][nt] = (f32x4){0.f, 0.f, 0.f, 0.f};
#pragma unroll
    for (int ks = 0; ks < 4; ++ks) {
        short8 bf[4];
#pragma unroll
        for (int nt = 0; nt < 4; ++nt)
            bf[nt] = *(const short8*)&zb[(size_t)(nt * 16 + n16) * 128 + ks * 32 + qd * 8];
#pragma unroll
        for (int mi = 0; mi < 4; ++mi) {
            int mt = w * 4 + mi;
            short8 af = *(const short8*)&apk2[(size_t)((mt * 4 + ks) * 64 + lane) * 8];
#pragma unroll
            for (int nt = 0; nt < 4; ++nt)
                acc[mi][nt] = __builtin_amdgcn_mfma_f32_16x16x32_bf16(af, bf[nt], acc[mi][nt], 0, 0, 0);
        }
    }
    const float* xb = x + (size_t)b * 256 * HWSZ;
    float* ob = out + (size_t)b * 256 * HWSZ;
#pragma unroll
    for (int mi = 0; mi < 4; ++mi)
#pragma unroll
        for (int nt = 0; nt < 4; ++nt)
#pragma unroll
            for (int r = 0; r < 4; ++r) {
                int o = w * 64 + mi * 16 + qd * 4 + r;
                size_t idx = (size_t)o * HWSZ + p0 + nt * 16 + n16;
                ob[idx] = xb[idx] + silu_f(acc[mi][nt][r] + bias3[o]);
            }
}

extern "C" void kernel_launch(void* const* d_in, const int* in_sizes, int n_in,
                              void* d_out, int out_size, void* d_ws, size_t ws_size,
                              hipStream_t stream) {
    const float* x     = (const float*)d_in[0];
    const float* cv1w  = (const float*)d_in[1];
    const float* bn1g  = (const float*)d_in[2];
    const float* bn1b  = (const float*)d_in[3];
    const float* bn1m  = (const float*)d_in[4];
    const float* bn1v  = (const float*)d_in[5];
    const float* offw  = (const float*)d_in[6];
    const float* offb  = (const float*)d_in[7];
    const float* dcnw  = (const float*)d_in[8];
    const float* dcnb  = (const float*)d_in[9];
    const float* bn2g  = (const float*)d_in[10];
    const float* bn2b  = (const float*)d_in[11];
    const float* bn2m  = (const float*)d_in[12];
    const float* bn2v  = (const float*)d_in[13];
    const float* cv2w  = (const float*)d_in[14];
    const float* bn3g  = (const float*)d_in[15];
    const float* bn3b  = (const float*)d_in[16];
    const float* bn3m  = (const float*)d_in[17];
    const float* bn3v  = (const float*)d_in[18];
    float* out = (float*)d_out;

    // workspace layout (float units)
    float* base = (float*)d_ws;
    unsigned short* y1t = (unsigned short*)base;                 // 8*6400*128 bf16
    float* raw   = base + 3276800;                               // 8*27*6400
    unsigned short* zt  = (unsigned short*)(base + 4659200);     // 8*6400*128 bf16
    unsigned short* apk1 = (unsigned short*)(base + 7936000);
    unsigned short* apko = (unsigned short*)(base + 7952384);
    unsigned short* apkd = (unsigned short*)(base + 7970816);
    unsigned short* apk2 = (unsigned short*)(base + 8044544);
    float* bias1 = base + 8060928;
    float* biaso = base + 8061056;
    float* bias2 = base + 8061088;
    float* bias3 = base + 8061216;

    k_prep<<<979, 256, 0, stream>>>(cv1w, bn1g, bn1b, bn1m, bn1v,
                                    offw, offb, dcnw, dcnb,
                                    bn2g, bn2b, bn2m, bn2v,
                                    cv2w, bn3g, bn3b, bn3m, bn3v,
                                    apk1, apko, apkd, apk2,
                                    bias1, biaso, bias2, bias3);
    k_cv1<<<800, 256, 0, stream>>>(x, apk1, bias1, y1t);
    k_off<<<800, 256, 0, stream>>>(y1t, apko, biaso, raw);
    k_dcn<<<1600, 256, 0, stream>>>(y1t, raw, apkd, bias2, zt);
    k_cv2<<<800, 256, 0, stream>>>(zt, x, apk2, bias3, out);
}